// Round 5
// baseline (131.636 us; speedup 1.0000x reference)
//
#include <hip/hip_runtime.h>

// (B,P,D,H,DB) = (2048,128,64,8,10)
// Algebraic factorization (P never meets a 64-dot):
//   xp = x@W_kvx + b_kvx + b_kvb   (both k- and v-half biases folded)  [K1]
//   q  = x@W_q + b_q                                                    [K1]
//   dots[p,h] = 0.125*(dot0[h] + sum_e b[p,e]*Wqkb[e,h])               [K2]
//     dot0[h]   = sum_d xp[h*64+d]*q[h,d]
//     Wqkb[e,h] = sum_d W_kvb[e,h*64+d]*q[h,d]
//   softmax over h; A[h]=sum_p attn; S[e,h]=sum_p attn*b[p,e]
//   vals[h,d] = A[h]*xp[512+h*64+d] + sum_e S[e,h]*W_kvb[e,512+h*64+d] [K2]
//   out = vals@W_f + b_f                                                [K3]
#define NDB 10

// ---------------------------------------------------------------------------
// K1: XQ[b][0..1023] = x@W_kvx + b_kvx + b_kvb ; XQ[b][1024..1535] = x@W_q + b_q
// 768 blocks (32 row-tiles x 24 col-tiles), 256 thr, 64x64 tile, 4x4/thread.
// ---------------------------------------------------------------------------
__global__ __launch_bounds__(256) void proj_kernel(
    const float* __restrict__ x, const float* __restrict__ W_kvx,
    const float* __restrict__ b_kvx, const float* __restrict__ b_kvb,
    const float* __restrict__ W_q, const float* __restrict__ b_q,
    float* __restrict__ XQ)
{
    __shared__ float x_t[64][68];          // [k][r], pad 68: b128 reads conflict-free
    const int t = threadIdx.x;
    const int row0 = blockIdx.x * 64;
    const int ct = blockIdx.y;             // 0..15 kvx-cols, 16..23 q-cols

    // stage x transposed (4 strided float4 loads, conflict-free LDS writes)
    {
        const int r = t & 63, kb = (t >> 6) * 16;
        float4 xv[4];
        #pragma unroll
        for (int i = 0; i < 4; ++i)
            xv[i] = *(const float4*)&x[(size_t)(row0 + r) * 64 + kb + i * 4];
        #pragma unroll
        for (int i = 0; i < 4; ++i) {
            x_t[kb + i * 4 + 0][r] = xv[i].x;
            x_t[kb + i * 4 + 1][r] = xv[i].y;
            x_t[kb + i * 4 + 2][r] = xv[i].z;
            x_t[kb + i * 4 + 3][r] = xv[i].w;
        }
    }
    __syncthreads();

    const bool iskv = (ct < 16);
    const int c0 = (iskv ? ct * 64 : (ct - 16) * 64) + (t & 15) * 4;
    const int stride = iskv ? 1024 : 512;
    const float* Wp = (iskv ? W_kvx : W_q) + c0;
    const int r0 = (t >> 4) * 4;

    float acc[4][4] = {};
    #pragma unroll 8
    for (int k = 0; k < 64; ++k) {
        float4 a  = *(const float4*)&x_t[k][r0];       // broadcast b128
        float4 wv = *(const float4*)&Wp[k * stride];   // coalesced 256B/16 lanes
        float av[4] = {a.x, a.y, a.z, a.w};
        float wvv[4] = {wv.x, wv.y, wv.z, wv.w};
        #pragma unroll
        for (int i = 0; i < 4; ++i)
            #pragma unroll
            for (int jj = 0; jj < 4; ++jj)
                acc[i][jj] = fmaf(av[i], wvv[jj], acc[i][jj]);
    }
    float4 bias;
    if (iskv) {
        float4 b1 = *(const float4*)&b_kvx[c0];
        float4 b2 = *(const float4*)&b_kvb[c0];
        bias.x = b1.x + b2.x; bias.y = b1.y + b2.y;
        bias.z = b1.z + b2.z; bias.w = b1.w + b2.w;
    } else {
        bias = *(const float4*)&b_q[c0];
    }
    const int outcol = ct * 64 + (t & 15) * 4;   // q cols land at 1024+ automatically
    #pragma unroll
    for (int i = 0; i < 4; ++i) {
        float4 o;
        o.x = acc[i][0] + bias.x; o.y = acc[i][1] + bias.y;
        o.z = acc[i][2] + bias.z; o.w = acc[i][3] + bias.w;
        *(float4*)&XQ[(size_t)(row0 + r0 + i) * 1536 + outcol] = o;
    }
}

// ---------------------------------------------------------------------------
// K2: attention core. 512 blocks x 256 thr; wave w owns row blockIdx.x*4+w.
// ZERO barriers — all LDS traffic is wave-private (compiler lgkmcnt orders it).
// ---------------------------------------------------------------------------
__global__ __launch_bounds__(256) void attn_core(
    const float* __restrict__ bmat, const float* __restrict__ W_kvb,
    const float* __restrict__ XQ, float* __restrict__ VALS)
{
    __shared__ float bb_s[4][128][11];     // p-stride 11: C2 reads ~2-way
    __shared__ float q_s[4][8][68];        // h-stride 68: bank=(4h+l+8m)%32, free
    __shared__ float dot0_s[4][8];
    __shared__ float Wqkb_s[4][NDB][8];
    __shared__ float A_s[4][8];
    __shared__ float S_s[4][NDB][8];

    const int t = threadIdx.x, lane = t & 63, w = t >> 6;
    const int row = blockIdx.x * 4 + w;
    const float* __restrict__ xq = XQ + (size_t)row * 1536;

    // stage q (own row): 2 coalesced float4 loads per lane
    {
        float4 a  = *(const float4*)&xq[1024 + lane * 4];
        float4 b4 = *(const float4*)&xq[1024 + 256 + lane * 4];
        int d0 = lane * 4;
        float av[4] = {a.x, a.y, a.z, a.w};
        float bv[4] = {b4.x, b4.y, b4.z, b4.w};
        #pragma unroll
        for (int c = 0; c < 4; ++c) {
            int d = d0 + c;
            q_s[w][d >> 6][d & 63] = av[c];
            int d2 = d + 256;
            q_s[w][d2 >> 6][d2 & 63] = bv[c];
        }
    }
    // stage bb (own row): 20 coalesced scalar loads per lane
    {
        const float* bsrc = bmat + (size_t)row * 1280;
        #pragma unroll
        for (int i = 0; i < 20; ++i) {
            int idx = lane + 64 * i;
            bb_s[w][idx / 10][idx % 10] = bsrc[idx];
        }
    }

    // dot0[h] + Wqkb[e][h]: 8-lane group h, member i8
    const int h = lane >> 3, i8 = lane & 7;
    {
        float s = 0.f;
        #pragma unroll
        for (int j = 0; j < 8; ++j) {
            int d = i8 + 8 * j;
            s = fmaf(xq[h * 64 + d], q_s[w][h][d], s);
        }
        s += __shfl_xor(s, 1); s += __shfl_xor(s, 2); s += __shfl_xor(s, 4);
        if (i8 == 0) dot0_s[w][h] = s;
    }
    #pragma unroll
    for (int e = 0; e < NDB; ++e) {
        float s = 0.f;
        #pragma unroll
        for (int m = 0; m < 8; ++m) {
            int d = i8 + 8 * m;
            s = fmaf(W_kvb[e * 1024 + h * 64 + d], q_s[w][h][d], s);
        }
        s += __shfl_xor(s, 1); s += __shfl_xor(s, 2); s += __shfl_xor(s, 4);
        if (i8 == 0) Wqkb_s[w][e][h] = s;
    }

    // dots + softmax(h) + A/S accumulation: lane = pg*8 + hh
    {
        const int hh = lane & 7, pg = lane >> 3;
        float aA = 0.f, aS[NDB];
        #pragma unroll
        for (int e = 0; e < NDB; ++e) aS[e] = 0.f;
        float wq[NDB];
        #pragma unroll
        for (int e = 0; e < NDB; ++e) wq[e] = Wqkb_s[w][e][hh];
        const float d0v = dot0_s[w][hh];
        #pragma unroll 4
        for (int it = 0; it < 16; ++it) {
            int p = pg + 8 * it;
            float bbv[NDB];
            #pragma unroll
            for (int e = 0; e < NDB; ++e) bbv[e] = bb_s[w][p][e];
            float dot = d0v;
            #pragma unroll
            for (int e = 0; e < NDB; ++e) dot = fmaf(bbv[e], wq[e], dot);
            dot *= 0.125f;
            float m = dot;
            m = fmaxf(m, __shfl_xor(m, 1));
            m = fmaxf(m, __shfl_xor(m, 2));
            m = fmaxf(m, __shfl_xor(m, 4));
            float ex = __expf(dot - m);
            float sum = ex;
            sum += __shfl_xor(sum, 1); sum += __shfl_xor(sum, 2); sum += __shfl_xor(sum, 4);
            float at = ex * __builtin_amdgcn_rcpf(sum);
            aA += at;
            #pragma unroll
            for (int e = 0; e < NDB; ++e) aS[e] = fmaf(at, bbv[e], aS[e]);
        }
        aA += __shfl_xor(aA, 8); aA += __shfl_xor(aA, 16); aA += __shfl_xor(aA, 32);
        #pragma unroll
        for (int e = 0; e < NDB; ++e) {
            aS[e] += __shfl_xor(aS[e], 8);
            aS[e] += __shfl_xor(aS[e], 16);
            aS[e] += __shfl_xor(aS[e], 32);
        }
        if (pg == 0) {
            A_s[w][hh] = aA;
            #pragma unroll
            for (int e = 0; e < NDB; ++e) S_s[w][e][hh] = aS[e];
        }
    }

    // vals (same wave): coalesced global reads/writes
    #pragma unroll
    for (int i = 0; i < 8; ++i) {
        int f = lane + 64 * i;             // h == i
        float v = A_s[w][i] * xq[512 + f];
        #pragma unroll
        for (int e = 0; e < NDB; ++e)
            v = fmaf(S_s[w][e][i], W_kvb[e * 1024 + 512 + f], v);
        VALS[(size_t)row * 512 + f] = v;
    }
}

// ---------------------------------------------------------------------------
// K3: out = VALS @ W_f + b_f. 512 blocks x 256 thr, 4 rows/block.
// W_f tiled 128x64 through LDS; VALS rows via wave-uniform scalar loads.
// ---------------------------------------------------------------------------
__global__ __launch_bounds__(256) void out_kernel(
    const float* __restrict__ VALS, const float* __restrict__ W_f,
    const float* __restrict__ b_f, float* __restrict__ out)
{
    __shared__ float wf_s[128][64];        // 32 KB tile
    const int t = threadIdx.x, j = t & 63;
    const int row = blockIdx.x * 4 + (t >> 6);
    const int rowU = __builtin_amdgcn_readfirstlane(row);   // force SGPR path
    const float4* vrow = (const float4*)(VALS + (size_t)rowU * 512);

    float acc = 0.f;
    #pragma unroll
    for (int kt = 0; kt < 4; ++kt) {
        __syncthreads();
        #pragma unroll
        for (int i = 0; i < 8; ++i) {
            int fi = t + 256 * i;          // float4 index in 8192-float tile
            ((float4*)wf_s)[fi] = ((const float4*)(W_f + kt * 128 * 64))[fi];
        }
        __syncthreads();
        #pragma unroll 8
        for (int k4 = 0; k4 < 32; ++k4) {
            float4 v = vrow[kt * 32 + k4]; // wave-uniform -> s_load, broadcast
            int k = k4 * 4;
            acc = fmaf(v.x, wf_s[k + 0][j], acc);
            acc = fmaf(v.y, wf_s[k + 1][j], acc);
            acc = fmaf(v.z, wf_s[k + 2][j], acc);
            acc = fmaf(v.w, wf_s[k + 3][j], acc);
        }
    }
    out[(size_t)row * 64 + j] = acc + b_f[j];
}

// ---------------------------------------------------------------------------
extern "C" void kernel_launch(void* const* d_in, const int* in_sizes, int n_in,
                              void* d_out, int out_size, void* d_ws, size_t ws_size,
                              hipStream_t stream)
{
    const float* x     = (const float*)d_in[0];
    const float* bmat  = (const float*)d_in[1];
    const float* W_kvx = (const float*)d_in[2];
    const float* b_kvx = (const float*)d_in[3];
    const float* W_kvb = (const float*)d_in[4];
    const float* b_kvb = (const float*)d_in[5];
    const float* W_q   = (const float*)d_in[6];
    const float* b_q   = (const float*)d_in[7];
    const float* W_f   = (const float*)d_in[8];
    const float* b_f   = (const float*)d_in[9];
    float* out  = (float*)d_out;
    float* XQ   = (float*)d_ws;                    // 2048*1536*4B = 12.6 MB
    float* VALS = XQ + (size_t)2048 * 1536;        // 2048*512*4B  =  4.2 MB

    proj_kernel<<<dim3(32, 24), 256, 0, stream>>>(x, W_kvx, b_kvx, b_kvb, W_q, b_q, XQ);
    attn_core<<<512, 256, 0, stream>>>(bmat, W_kvb, XQ, VALS);
    out_kernel<<<512, 256, 0, stream>>>(VALS, W_f, b_f, out);
}

// Round 6
// 109.155 us; speedup vs baseline: 1.2060x; 1.2060x over previous
//
#include <hip/hip_runtime.h>

// (B,P,D,H,DB) = (2048,128,64,8,10)
// Factorization:
//   XQ[b] = [x@W_kvx + b_kvx + b_kvb  (1024) || x@W_q + b_q (512)]      [K1]
//   dots[p,h] = 0.125*(dot0[h] + sum_e b[p,e]*Wqkb[e,h])                [K2]
//     dot0[h]   = sum_d xq[h*64+d]*xq[1024+h*64+d]
//     Wqkb[e,h] = sum_d W_kvb[e,h*64+d]*q[h,d]
//   softmax over h; A[h]=sum_p attn; S[e,h]=sum_p attn*b[p,e]
//   vals[f]  = A[f>>6]*xq[512+f] + sum_e S[e,f>>6]*W_kvb[e,512+f]       [K2]
//   out = vals@W_f + b_f                                                [K2, fused]
// K2 layout: ONE ROW PER BLOCK (4 waves collaborate) -> 2048 blocks,
// 8 blocks/CU, 32 waves/CU. Short per-wave critical path + real TLP.
#define NDB 10

// ---------------------------------------------------------------------------
// K1: proj GEMM. 768 blocks (32 row-tiles x 24 col-tiles), 64x64 tile.
// ---------------------------------------------------------------------------
__global__ __launch_bounds__(256) void proj_kernel(
    const float* __restrict__ x, const float* __restrict__ W_kvx,
    const float* __restrict__ b_kvx, const float* __restrict__ b_kvb,
    const float* __restrict__ W_q, const float* __restrict__ b_q,
    float* __restrict__ XQ)
{
    __shared__ float x_t[64][68];
    const int t = threadIdx.x;
    const int row0 = blockIdx.x * 64;
    const int ct = blockIdx.y;

    {
        const int r = t & 63, kb = (t >> 6) * 16;
        float4 xv[4];
        #pragma unroll
        for (int i = 0; i < 4; ++i)
            xv[i] = *(const float4*)&x[(size_t)(row0 + r) * 64 + kb + i * 4];
        #pragma unroll
        for (int i = 0; i < 4; ++i) {
            x_t[kb + i * 4 + 0][r] = xv[i].x;
            x_t[kb + i * 4 + 1][r] = xv[i].y;
            x_t[kb + i * 4 + 2][r] = xv[i].z;
            x_t[kb + i * 4 + 3][r] = xv[i].w;
        }
    }
    __syncthreads();

    const bool iskv = (ct < 16);
    const int c0 = (iskv ? ct * 64 : (ct - 16) * 64) + (t & 15) * 4;
    const int stride = iskv ? 1024 : 512;
    const float* Wp = (iskv ? W_kvx : W_q) + c0;
    const int r0 = (t >> 4) * 4;

    float acc[4][4] = {};
    #pragma unroll 8
    for (int k = 0; k < 64; ++k) {
        float4 a  = *(const float4*)&x_t[k][r0];
        float4 wv = *(const float4*)&Wp[k * stride];
        float av[4] = {a.x, a.y, a.z, a.w};
        float wvv[4] = {wv.x, wv.y, wv.z, wv.w};
        #pragma unroll
        for (int i = 0; i < 4; ++i)
            #pragma unroll
            for (int jj = 0; jj < 4; ++jj)
                acc[i][jj] = fmaf(av[i], wvv[jj], acc[i][jj]);
    }
    float4 bias;
    if (iskv) {
        float4 b1 = *(const float4*)&b_kvx[c0];
        float4 b2 = *(const float4*)&b_kvb[c0];
        bias.x = b1.x + b2.x; bias.y = b1.y + b2.y;
        bias.z = b1.z + b2.z; bias.w = b1.w + b2.w;
    } else {
        bias = *(const float4*)&b_q[c0];
    }
    const int outcol = ct * 64 + (t & 15) * 4;
    #pragma unroll
    for (int i = 0; i < 4; ++i) {
        float4 o;
        o.x = acc[i][0] + bias.x; o.y = acc[i][1] + bias.y;
        o.z = acc[i][2] + bias.z; o.w = acc[i][3] + bias.w;
        *(float4*)&XQ[(size_t)(row0 + r0 + i) * 1536 + outcol] = o;
    }
}

// ---------------------------------------------------------------------------
// K2: attention core + out GEMM. One batch row per block, 4 waves collaborate.
// 2048 blocks x 256 thr -> 8 blocks/CU, 32 waves/CU.
// ---------------------------------------------------------------------------
__global__ __launch_bounds__(256) void attn_core(
    const float* __restrict__ bmat, const float* __restrict__ W_kvb,
    const float* __restrict__ XQ, const float* __restrict__ W_f,
    const float* __restrict__ b_f, float* __restrict__ out)
{
    __shared__ float bb_s[128][11];     // p-stride 11: conflict-free pg reads
    __shared__ float q_s[8][68];        // h-stride 68: Wqkb reads ~2-way
    __shared__ float dot0_s[8];
    __shared__ float Wqkb_s[NDB][8];
    __shared__ float partA[4][8];
    __shared__ float partS[4][NDB][8];
    __shared__ float A_s[8];
    __shared__ float S_s[NDB][8];
    __shared__ float vals_s[512];
    __shared__ float pout[4][64];

    const int t = threadIdx.x, lane = t & 63, w = t >> 6;
    const int row = blockIdx.x;
    const float* __restrict__ xq = XQ + (size_t)row * 1536;

    // ---- stage: bb (5 coalesced loads/thread), q into LDS (2/thread) ----
    {
        const float* bsrc = bmat + (size_t)row * 1280;
        #pragma unroll
        for (int i = 0; i < 5; ++i) {
            int idx = t + 256 * i;
            bb_s[idx / 10][idx % 10] = bsrc[idx];
        }
        float qa = xq[1024 + t];
        float qb = xq[1024 + 256 + t];
        q_s[t >> 6][t & 63] = qa;
        q_s[(t + 256) >> 6][t & 63] = qb;
        // ---- dot0: wave w reduces h=w (f=t) and h=w+4 (f=t+256) ----
        float p1 = xq[t] * qa;            // xq[f]*q[f], f=t
        float p2 = xq[t + 256] * qb;      // f=t+256
        #pragma unroll
        for (int m = 1; m <= 32; m <<= 1) p1 += __shfl_xor(p1, m);
        #pragma unroll
        for (int m = 1; m <= 32; m <<= 1) p2 += __shfl_xor(p2, m);
        if (lane == 0) { dot0_s[w] = p1; dot0_s[w + 4] = p2; }
    }
    __syncthreads();                                   // B1

    // ---- Wqkb: 80 dots of 64, 32 block-wide 8-lane groups, <=3 rounds ----
    {
        const int g = t >> 3, l = t & 7;
        #pragma unroll
        for (int ro = 0; ro < 3; ++ro) {
            int o = g + 32 * ro;
            if (o < 80) {
                int e = o >> 3, h = o & 7;
                float s = 0.f;
                #pragma unroll
                for (int m = 0; m < 8; ++m) {
                    int d = l + 8 * m;
                    s = fmaf(W_kvb[e * 1024 + h * 64 + d], q_s[h][d], s);
                }
                s += __shfl_xor(s, 1); s += __shfl_xor(s, 2); s += __shfl_xor(s, 4);
                if (l == 0) Wqkb_s[e][h] = s;
            }
        }
    }
    __syncthreads();                                   // B2

    // ---- C2: wave w handles p in [w*32, w*32+32); softmax over h in 8-lane grp
    {
        const int hh = lane & 7, pg = lane >> 3;
        float wq[NDB];
        #pragma unroll
        for (int e = 0; e < NDB; ++e) wq[e] = Wqkb_s[e][hh];
        const float d0v = dot0_s[hh];
        float aA = 0.f, aS[NDB];
        #pragma unroll
        for (int e = 0; e < NDB; ++e) aS[e] = 0.f;
        #pragma unroll
        for (int it = 0; it < 4; ++it) {
            int p = w * 32 + pg + 8 * it;
            float bbv[NDB];
            #pragma unroll
            for (int e = 0; e < NDB; ++e) bbv[e] = bb_s[p][e];
            float dot = d0v;
            #pragma unroll
            for (int e = 0; e < NDB; ++e) dot = fmaf(bbv[e], wq[e], dot);
            dot *= 0.125f;
            float m = dot;
            m = fmaxf(m, __shfl_xor(m, 1));
            m = fmaxf(m, __shfl_xor(m, 2));
            m = fmaxf(m, __shfl_xor(m, 4));
            float ex = __expf(dot - m);
            float sum = ex;
            sum += __shfl_xor(sum, 1); sum += __shfl_xor(sum, 2); sum += __shfl_xor(sum, 4);
            float at = ex * __builtin_amdgcn_rcpf(sum);
            aA += at;
            #pragma unroll
            for (int e = 0; e < NDB; ++e) aS[e] = fmaf(at, bbv[e], aS[e]);
        }
        aA += __shfl_xor(aA, 8); aA += __shfl_xor(aA, 16); aA += __shfl_xor(aA, 32);
        #pragma unroll
        for (int e = 0; e < NDB; ++e) {
            aS[e] += __shfl_xor(aS[e], 8);
            aS[e] += __shfl_xor(aS[e], 16);
            aS[e] += __shfl_xor(aS[e], 32);
        }
        if (pg == 0) {
            partA[w][hh] = aA;
            #pragma unroll
            for (int e = 0; e < NDB; ++e) partS[w][e][hh] = aS[e];
        }
    }
    __syncthreads();                                   // B3

    if (t < 8)  A_s[t] = partA[0][t] + partA[1][t] + partA[2][t] + partA[3][t];
    if (t < 80) {
        int e = t >> 3, h = t & 7;
        S_s[e][h] = partS[0][e][h] + partS[1][e][h] + partS[2][e][h] + partS[3][e][h];
    }
    __syncthreads();                                   // B4

    // ---- vals: thread t computes f=t (h=w) and f=t+256 (h=w+4) ----
    {
        int f1 = t, f2 = t + 256;
        float v1 = A_s[w] * xq[512 + f1];
        float v2 = A_s[w + 4] * xq[512 + f2];
        #pragma unroll
        for (int e = 0; e < NDB; ++e) {
            v1 = fmaf(S_s[e][w],     W_kvb[e * 1024 + 512 + f1], v1);
            v2 = fmaf(S_s[e][w + 4], W_kvb[e * 1024 + 512 + f2], v2);
        }
        vals_s[f1] = v1;
        vals_s[f2] = v2;
    }
    __syncthreads();                                   // B5

    // ---- out GEMM: wave w handles f-slice [w*128, w*128+128), lane j ----
    {
        const int j = lane;
        float acc = 0.f;
        #pragma unroll 8
        for (int k4 = 0; k4 < 32; ++k4) {
            int f = w * 128 + k4 * 4;
            float4 v = *(const float4*)&vals_s[f];     // wave-uniform broadcast
            acc = fmaf(v.x, W_f[(f + 0) * 64 + j], acc);
            acc = fmaf(v.y, W_f[(f + 1) * 64 + j], acc);
            acc = fmaf(v.z, W_f[(f + 2) * 64 + j], acc);
            acc = fmaf(v.w, W_f[(f + 3) * 64 + j], acc);
        }
        pout[w][j] = acc;
    }
    __syncthreads();                                   // B6

    if (t < 64)
        out[(size_t)row * 64 + t] =
            pout[0][t] + pout[1][t] + pout[2][t] + pout[3][t] + b_f[t];
}

// ---------------------------------------------------------------------------
extern "C" void kernel_launch(void* const* d_in, const int* in_sizes, int n_in,
                              void* d_out, int out_size, void* d_ws, size_t ws_size,
                              hipStream_t stream)
{
    const float* x     = (const float*)d_in[0];
    const float* bmat  = (const float*)d_in[1];
    const float* W_kvx = (const float*)d_in[2];
    const float* b_kvx = (const float*)d_in[3];
    const float* W_kvb = (const float*)d_in[4];
    const float* b_kvb = (const float*)d_in[5];
    const float* W_q   = (const float*)d_in[6];
    const float* b_q   = (const float*)d_in[7];
    const float* W_f   = (const float*)d_in[8];
    const float* b_f   = (const float*)d_in[9];
    float* out = (float*)d_out;
    float* XQ  = (float*)d_ws;                 // 2048*1536*4B = 12.6 MB

    proj_kernel<<<dim3(32, 24), 256, 0, stream>>>(x, W_kvx, b_kvx, b_kvb, W_q, b_q, XQ);
    attn_core<<<2048, 256, 0, stream>>>(bmat, W_kvb, XQ, W_f, b_f, out);
}

// Round 7
// 106.747 us; speedup vs baseline: 1.2332x; 1.0226x over previous
//
#include <hip/hip_runtime.h>

// (B,P,D,H,DB) = (2048,128,64,8,10)
// Factorization v2 — v-path folded through W_f:
//   K0: M[i,h*64+j] = sum_d W_kvx[i,512+h*64+d]*W_f[(h*64+d)*64+j]   (fixed)
//       T[e,h*64+j] = sum_d W_kvb[e,512+h*64+d]*W_f[(h*64+d)*64+j]   (fixed)
//       c[h*64+j]   = sum_d (b_kvx+b_kvb)[512+h*64+d]*W_f[...]       (fixed)
//   K1: XU[b] = [ x@W_kvx_k + b_kvx_k + b_kvb_k (512) | x@W_q + b_q (512)
//                | x@M + c (512) ]
//   K2: dots[p,h] = 0.125*(dot0[h] + sum_e b[p,e]*Wqkb[e,h]); softmax over h
//       A[h]=sum_p attn; S[e,h]=sum_p attn*b[p,e]
//       out[b,j] = b_f[j] + sum_h A[h]*U[h*64+j] + sum_{e,h} S[e,h]*T[e,h*64+j]
#define NDB 10

// ---------------------------------------------------------------------------
// K0: fold v-half weights through W_f. grid (75,2) x 256 thr.
// rows 0-63 -> M, 64-73 -> T, 74 -> c. Each thread: one col (512-dot of 64).
// ---------------------------------------------------------------------------
__global__ __launch_bounds__(256) void fold_kernel(
    const float* __restrict__ W_kvx, const float* __restrict__ b_kvx,
    const float* __restrict__ W_kvb, const float* __restrict__ b_kvb,
    const float* __restrict__ W_f, float* __restrict__ M,
    float* __restrict__ c, float* __restrict__ T)
{
    const int r = blockIdx.x;              // 0..74
    const int col = blockIdx.y * 256 + threadIdx.x;   // 0..511
    const int h = col >> 6, j = col & 63;  // h wave-uniform (col>>6 over 64-lane span)

    const float* wfp = W_f + (size_t)(h * 64) * 64 + j;   // stride-64 reads, j coalesced
    float acc = 0.f;
    if (r < 64) {
        const float* src = W_kvx + (size_t)r * 1024 + 512 + h * 64;
        #pragma unroll 8
        for (int d = 0; d < 64; ++d) acc = fmaf(src[d], wfp[d * 64], acc);
        M[(size_t)r * 512 + col] = acc;
    } else if (r < 74) {
        const int e = r - 64;
        const float* src = W_kvb + (size_t)e * 1024 + 512 + h * 64;
        #pragma unroll 8
        for (int d = 0; d < 64; ++d) acc = fmaf(src[d], wfp[d * 64], acc);
        T[(size_t)e * 512 + col] = acc;
    } else {
        const float* s1 = b_kvx + 512 + h * 64;
        const float* s2 = b_kvb + 512 + h * 64;
        #pragma unroll 8
        for (int d = 0; d < 64; ++d) acc = fmaf(s1[d] + s2[d], wfp[d * 64], acc);
        c[col] = acc;
    }
}

// ---------------------------------------------------------------------------
// K1: proj GEMM -> XU[2048][1536]. 768 blocks (32 rt x 24 ct), 64x64 tile.
// ct 0-7: W_kvx k-half; 8-15: W_q; 16-23: M (folded v-path).
// ---------------------------------------------------------------------------
__global__ __launch_bounds__(256) void proj_kernel(
    const float* __restrict__ x, const float* __restrict__ W_kvx,
    const float* __restrict__ b_kvx, const float* __restrict__ b_kvb,
    const float* __restrict__ W_q, const float* __restrict__ b_q,
    const float* __restrict__ M, const float* __restrict__ c,
    float* __restrict__ XU)
{
    __shared__ float x_t[64][68];
    const int t = threadIdx.x;
    const int row0 = blockIdx.x * 64;
    const int ct = blockIdx.y;

    {
        const int r = t & 63, kb = (t >> 6) * 16;
        float4 xv[4];
        #pragma unroll
        for (int i = 0; i < 4; ++i)
            xv[i] = *(const float4*)&x[(size_t)(row0 + r) * 64 + kb + i * 4];
        #pragma unroll
        for (int i = 0; i < 4; ++i) {
            x_t[kb + i * 4 + 0][r] = xv[i].x;
            x_t[kb + i * 4 + 1][r] = xv[i].y;
            x_t[kb + i * 4 + 2][r] = xv[i].z;
            x_t[kb + i * 4 + 3][r] = xv[i].w;
        }
    }
    __syncthreads();

    const int cc = (t & 15) * 4;
    const float* Wp; int stride, c0;
    if (ct < 8)       { Wp = W_kvx; stride = 1024; c0 = ct * 64 + cc; }
    else if (ct < 16) { Wp = W_q;   stride = 512;  c0 = (ct - 8) * 64 + cc; }
    else              { Wp = M;     stride = 512;  c0 = (ct - 16) * 64 + cc; }
    Wp += c0;
    const int r0 = (t >> 4) * 4;

    float acc[4][4] = {};
    #pragma unroll 8
    for (int k = 0; k < 64; ++k) {
        float4 a  = *(const float4*)&x_t[k][r0];
        float4 wv = *(const float4*)&Wp[k * stride];
        float av[4] = {a.x, a.y, a.z, a.w};
        float wvv[4] = {wv.x, wv.y, wv.z, wv.w};
        #pragma unroll
        for (int i = 0; i < 4; ++i)
            #pragma unroll
            for (int jj = 0; jj < 4; ++jj)
                acc[i][jj] = fmaf(av[i], wvv[jj], acc[i][jj]);
    }
    float4 bias;
    if (ct < 8) {
        float4 b1 = *(const float4*)&b_kvx[c0];
        float4 b2 = *(const float4*)&b_kvb[c0];
        bias.x = b1.x + b2.x; bias.y = b1.y + b2.y;
        bias.z = b1.z + b2.z; bias.w = b1.w + b2.w;
    } else if (ct < 16) {
        bias = *(const float4*)&b_q[c0];
    } else {
        bias = *(const float4*)&c[c0];
    }
    const int outcol = ct * 64 + cc;
    #pragma unroll
    for (int i = 0; i < 4; ++i) {
        float4 o;
        o.x = acc[i][0] + bias.x; o.y = acc[i][1] + bias.y;
        o.z = acc[i][2] + bias.z; o.w = acc[i][3] + bias.w;
        *(float4*)&XU[(size_t)(row0 + r0 + i) * 1536 + outcol] = o;
    }
}

// ---------------------------------------------------------------------------
// K2: attention core. One row per block, 4 waves. 2048 blocks x 256 thr.
// Tail reads per-row U (from XU) + L1-hot T instead of vals/out-GEMM.
// ---------------------------------------------------------------------------
__global__ __launch_bounds__(256) void attn_core(
    const float* __restrict__ bmat, const float* __restrict__ W_kvb,
    const float* __restrict__ XU, const float* __restrict__ T,
    const float* __restrict__ b_f, float* __restrict__ out)
{
    __shared__ float bb_s[128][11];
    __shared__ float q_s[8][68];
    __shared__ float dot0_s[8];
    __shared__ float Wqkb_s[NDB][8];
    __shared__ float partA[4][8];
    __shared__ float partS[4][NDB][8];
    __shared__ float A_s[8];
    __shared__ float S_s[NDB][8];
    __shared__ float pout[4][64];

    const int t = threadIdx.x, lane = t & 63, w = t >> 6;
    const int row = blockIdx.x;
    const float* __restrict__ xq = XU + (size_t)row * 1536;

    // ---- stage bb + q; dot0 via full-wave reduce ----
    {
        const float* bsrc = bmat + (size_t)row * 1280;
        #pragma unroll
        for (int i = 0; i < 5; ++i) {
            int idx = t + 256 * i;
            bb_s[idx / 10][idx % 10] = bsrc[idx];
        }
        float qa = xq[512 + t];            // q feature f=t   (h = w)
        float qb = xq[512 + 256 + t];      // q feature f=t+256 (h = w+4)
        q_s[t >> 6][t & 63] = qa;
        q_s[(t + 256) >> 6][t & 63] = qb;
        float p1 = xq[t] * qa;             // xp_k[f]*q[f]
        float p2 = xq[t + 256] * qb;
        #pragma unroll
        for (int m = 1; m <= 32; m <<= 1) p1 += __shfl_xor(p1, m);
        #pragma unroll
        for (int m = 1; m <= 32; m <<= 1) p2 += __shfl_xor(p2, m);
        if (lane == 0) { dot0_s[w] = p1; dot0_s[w + 4] = p2; }
    }
    __syncthreads();                                   // B1

    // ---- Wqkb: 80 dots of 64 over k-half of W_kvb ----
    {
        const int g = t >> 3, l = t & 7;
        #pragma unroll
        for (int ro = 0; ro < 3; ++ro) {
            int o = g + 32 * ro;
            if (o < 80) {
                int e = o >> 3, h = o & 7;
                float s = 0.f;
                #pragma unroll
                for (int m = 0; m < 8; ++m) {
                    int d = l + 8 * m;
                    s = fmaf(W_kvb[e * 1024 + h * 64 + d], q_s[h][d], s);
                }
                s += __shfl_xor(s, 1); s += __shfl_xor(s, 2); s += __shfl_xor(s, 4);
                if (l == 0) Wqkb_s[e][h] = s;
            }
        }
    }
    __syncthreads();                                   // B2

    // ---- softmax over h + A/S accumulation; wave w: p in [w*32, w*32+32) ----
    {
        const int hh = lane & 7, pg = lane >> 3;
        float wq[NDB];
        #pragma unroll
        for (int e = 0; e < NDB; ++e) wq[e] = Wqkb_s[e][hh];
        const float d0v = dot0_s[hh];
        float aA = 0.f, aS[NDB];
        #pragma unroll
        for (int e = 0; e < NDB; ++e) aS[e] = 0.f;
        #pragma unroll
        for (int it = 0; it < 4; ++it) {
            int p = w * 32 + pg + 8 * it;
            float bbv[NDB];
            #pragma unroll
            for (int e = 0; e < NDB; ++e) bbv[e] = bb_s[p][e];
            float dot = d0v;
            #pragma unroll
            for (int e = 0; e < NDB; ++e) dot = fmaf(bbv[e], wq[e], dot);
            dot *= 0.125f;
            float m = dot;
            m = fmaxf(m, __shfl_xor(m, 1));
            m = fmaxf(m, __shfl_xor(m, 2));
            m = fmaxf(m, __shfl_xor(m, 4));
            float ex = __expf(dot - m);
            float sum = ex;
            sum += __shfl_xor(sum, 1); sum += __shfl_xor(sum, 2); sum += __shfl_xor(sum, 4);
            float at = ex * __builtin_amdgcn_rcpf(sum);
            aA += at;
            #pragma unroll
            for (int e = 0; e < NDB; ++e) aS[e] = fmaf(at, bbv[e], aS[e]);
        }
        aA += __shfl_xor(aA, 8); aA += __shfl_xor(aA, 16); aA += __shfl_xor(aA, 32);
        #pragma unroll
        for (int e = 0; e < NDB; ++e) {
            aS[e] += __shfl_xor(aS[e], 8);
            aS[e] += __shfl_xor(aS[e], 16);
            aS[e] += __shfl_xor(aS[e], 32);
        }
        if (pg == 0) {
            partA[w][hh] = aA;
            #pragma unroll
            for (int e = 0; e < NDB; ++e) partS[w][e][hh] = aS[e];
        }
    }
    __syncthreads();                                   // B3

    if (t < 8)  A_s[t] = partA[0][t] + partA[1][t] + partA[2][t] + partA[3][t];
    if (t < 80) {
        int e = t >> 3, h = t & 7;
        S_s[e][h] = partS[0][e][h] + partS[1][e][h] + partS[2][e][h] + partS[3][e][h];
    }
    __syncthreads();                                   // B4

    // ---- tail: out[j] = b_f + sum_h A*U + sum_{e,h} S*T ; wave w: h in {2w,2w+1}
    {
        const int j = lane;
        float acc = 0.f;
        #pragma unroll
        for (int hi = 0; hi < 2; ++hi) {
            int h = 2 * w + hi;
            acc = fmaf(A_s[h], xq[1024 + h * 64 + j], acc);   // U from XU
            #pragma unroll
            for (int e = 0; e < NDB; ++e)
                acc = fmaf(S_s[e][h], T[e * 512 + h * 64 + j], acc);
        }
        pout[w][j] = acc;
    }
    __syncthreads();                                   // B5

    if (t < 64)
        out[(size_t)row * 64 + t] =
            pout[0][t] + pout[1][t] + pout[2][t] + pout[3][t] + b_f[t];
}

// ---------------------------------------------------------------------------
extern "C" void kernel_launch(void* const* d_in, const int* in_sizes, int n_in,
                              void* d_out, int out_size, void* d_ws, size_t ws_size,
                              hipStream_t stream)
{
    const float* x     = (const float*)d_in[0];
    const float* bmat  = (const float*)d_in[1];
    const float* W_kvx = (const float*)d_in[2];
    const float* b_kvx = (const float*)d_in[3];
    const float* W_kvb = (const float*)d_in[4];
    const float* b_kvb = (const float*)d_in[5];
    const float* W_q   = (const float*)d_in[6];
    const float* b_q   = (const float*)d_in[7];
    const float* W_f   = (const float*)d_in[8];
    const float* b_f   = (const float*)d_in[9];
    float* out = (float*)d_out;

    float* XU = (float*)d_ws;                      // 2048*1536 = 12.6 MB
    float* M  = XU + (size_t)2048 * 1536;          // 64*512
    float* c  = M + 64 * 512;                      // 512
    float* T  = c + 512;                           // 10*512

    fold_kernel<<<dim3(75, 2), 256, 0, stream>>>(W_kvx, b_kvx, W_kvb, b_kvb, W_f, M, c, T);
    proj_kernel<<<dim3(32, 24), 256, 0, stream>>>(x, W_kvx, b_kvx, b_kvb, W_q, b_q, M, c, XU);
    attn_core<<<2048, 256, 0, stream>>>(bmat, W_kvb, XU, T, b_f, out);
}